// Round 1
// baseline (129.216 us; speedup 1.0000x reference)
//
#include <hip/hip_runtime.h>

typedef __attribute__((ext_vector_type(8))) short short8;
typedef __attribute__((ext_vector_type(4))) float f32x4;

__device__ __forceinline__ unsigned short f2bf(float f) {
  union { float f; unsigned u; } v; v.f = f;
  unsigned r = v.u + 0x7FFFu + ((v.u >> 16) & 1u);
  return (unsigned short)(r >> 16);
}

// ---- problem constants ----
// x: (8,64,64,128) f32 ; offset: (8,64,64,18) ; modulation: (8,64,64,9)
// conv_kernel: (3,3,128,256) ; bias: (256,) ; out: (8,64,64,256) f32
// GEMM view: M=32768 (b,oh,ow), K=1152 ((dy*3+dx)*128+c), N=256 (f)
// A[m,kk] = feats[b, (3*oh+dy)%64, ow, ((3*oh+dy)/64)*3+dx, c]
constexpr int KKt = 1152;
constexpr int Ff  = 256;

// Transpose+convert conv_kernel (flat [kk][f] f32) -> Wt [f][kk] bf16 in d_ws.
__global__ void wt_transpose(const float* __restrict__ kf, unsigned short* __restrict__ wt) {
  int idx = blockIdx.x * 256 + threadIdx.x;   // idx = f*KKt + kk
  if (idx >= KKt * Ff) return;
  int f = idx / KKt, kk = idx - f * KKt;
  wt[idx] = f2bf(kf[kk * Ff + f]);
}

__global__ __launch_bounds__(256, 2) void dcn_main(
    const float* __restrict__ x, const float* __restrict__ off,
    const float* __restrict__ mo, const unsigned short* __restrict__ wt,
    const float* __restrict__ bias, float* __restrict__ out) {
  __shared__ unsigned short Asm[64 * 128];     // A-tile chunk, XOR-swizzled, 16 KB

  const int b  = blockIdx.x >> 6;
  const int oh = blockIdx.x & 63;
  const int t  = threadIdx.x;
  const int lane = t & 63;
  const int wv   = t >> 6;          // wave 0..3 -> F cols [wv*64, wv*64+64)
  const int fr   = lane & 15;       // fragment row/col within 16
  const int kg   = lane >> 4;       // k-octet group 0..3
  // staging role: 4 threads per output row (ow), 32 channels each
  const int sow = t >> 2;
  const int cb  = (t & 3) << 5;

  f32x4 acc[4][4];
#pragma unroll
  for (int i = 0; i < 4; ++i)
#pragma unroll
    for (int j = 0; j < 4; ++j) acc[i][j] = f32x4{0.f, 0.f, 0.f, 0.f};

  for (int ch = 0; ch < 9; ++ch) {
    const int dy  = ch / 3;
    const int dxk = ch - dy * 3;
    const int r   = 3 * oh + dy;
    const int hp  = r & 63;               // source pixel row h'
    const int kp  = (r >> 6) * 3 + dxk;   // tap index k' in 0..8

    // ---------- stage feats chunk (64 rows x 128 ch) into LDS as bf16 ----------
    {
      const int pix = (b * 64 + hp) * 64 + sow;
      const float oy = off[pix * 18 + kp];
      const float ox = off[pix * 18 + 9 + kp];
      const float mm = mo[pix * 9 + kp];
      // p = offset + (h'+1, ow+1) + (ky, kx), ky=kp/3-1, kx=kp%3-1
      const float py = oy + (float)(hp + kp / 3);
      const float px = ox + (float)(sow + kp % 3);
      const float y0f = floorf(py), x0f = floorf(px);
      const float y0 = fminf(fmaxf(y0f, 0.f), 65.f);
      const float y1 = fminf(fmaxf(y0f + 1.f, 0.f), 65.f);
      const float x0 = fminf(fmaxf(x0f, 0.f), 65.f);
      const float x1 = fminf(fmaxf(x0f + 1.f, 0.f), 65.f);
      const float ly = fminf(fmaxf(py, 0.f), 65.f) - y0;
      const float lx = fminf(fmaxf(px, 0.f), 65.f) - x0;
      // reference's (quirky) weight<->corner pairing, matched exactly:
      float w00 = (1.f - ly) * (1.f - lx) * mm;   // gather(y0,x0)
      float w01 = (1.f - ly) * lx * mm;           // gather(y1,x0)
      float w10 = ly * (1.f - lx) * mm;           // gather(y0,x1)
      float w11 = ly * lx * mm;                   // gather(y1,x1)
      const int iy0 = (int)y0, iy1 = (int)y1, ix0 = (int)x0, ix1 = (int)x1;
      const bool v00 = (iy0 >= 1) & (iy0 <= 64) & (ix0 >= 1) & (ix0 <= 64);
      const bool v01 = (iy1 >= 1) & (iy1 <= 64) & (ix0 >= 1) & (ix0 <= 64);
      const bool v10 = (iy0 >= 1) & (iy0 <= 64) & (ix1 >= 1) & (ix1 <= 64);
      const bool v11 = (iy1 >= 1) & (iy1 <= 64) & (ix1 >= 1) & (ix1 <= 64);
      int o00 = ((b * 64 + iy0 - 1) * 64 + (ix0 - 1)) * 128 + cb;
      int o01 = ((b * 64 + iy1 - 1) * 64 + (ix0 - 1)) * 128 + cb;
      int o10 = ((b * 64 + iy0 - 1) * 64 + (ix1 - 1)) * 128 + cb;
      int o11 = ((b * 64 + iy1 - 1) * 64 + (ix1 - 1)) * 128 + cb;
      if (!v00) { o00 = 0; w00 = 0.f; }
      if (!v01) { o01 = 0; w01 = 0.f; }
      if (!v10) { o10 = 0; w10 = 0.f; }
      if (!v11) { o11 = 0; w11 = 0.f; }
      const f32x4* p00 = (const f32x4*)(x + o00);
      const f32x4* p01 = (const f32x4*)(x + o01);
      const f32x4* p10 = (const f32x4*)(x + o10);
      const f32x4* p11 = (const f32x4*)(x + o11);
      char* lrow = (char*)Asm + sow * 256;
      const int swz = (sow & 7) << 4;
#pragma unroll
      for (int i8 = 0; i8 < 4; ++i8) {
        f32x4 a0 = p00[i8 * 2], a1 = p00[i8 * 2 + 1];
        f32x4 b0 = p01[i8 * 2], b1 = p01[i8 * 2 + 1];
        f32x4 c0 = p10[i8 * 2], c1 = p10[i8 * 2 + 1];
        f32x4 d0 = p11[i8 * 2], d1 = p11[i8 * 2 + 1];
        f32x4 ra = w00 * a0 + w01 * b0 + w10 * c0 + w11 * d0;
        f32x4 rb = w00 * a1 + w01 * b1 + w10 * c1 + w11 * d1;
        short8 pk;
        pk[0] = (short)f2bf(ra.x); pk[1] = (short)f2bf(ra.y);
        pk[2] = (short)f2bf(ra.z); pk[3] = (short)f2bf(ra.w);
        pk[4] = (short)f2bf(rb.x); pk[5] = (short)f2bf(rb.y);
        pk[6] = (short)f2bf(rb.z); pk[7] = (short)f2bf(rb.w);
        *(short8*)(lrow + (((cb << 1) + i8 * 16) ^ swz)) = pk;
      }
    }
    __syncthreads();

    // ---------- GEMM: 4 k-steps of 32 over this 128-chunk ----------
#pragma unroll
    for (int ks = 0; ks < 4; ++ks) {
      short8 af[4], bfr[4];
#pragma unroll
      for (int m2 = 0; m2 < 4; ++m2) {
        const int rw = m2 * 16 + fr;
        af[m2] = *(const short8*)((const char*)Asm + rw * 256 +
                                  ((ks * 64 + kg * 16) ^ ((rw & 7) << 4)));
      }
#pragma unroll
      for (int nb = 0; nb < 4; ++nb) {
        const int f = wv * 64 + nb * 16 + fr;
        bfr[nb] = *(const short8*)(wt + f * KKt + ch * 128 + ks * 32 + kg * 8);
      }
#pragma unroll
      for (int m2 = 0; m2 < 4; ++m2)
#pragma unroll
        for (int nb = 0; nb < 4; ++nb)
          acc[m2][nb] = __builtin_amdgcn_mfma_f32_16x16x32_bf16(af[m2], bfr[nb], acc[m2][nb], 0, 0, 0);
    }
    __syncthreads();
  }

  // ---------- epilogue: D layout col=lane&15, row=(lane>>4)*4+reg ----------
  float bs[4];
#pragma unroll
  for (int nb = 0; nb < 4; ++nb) bs[nb] = bias[wv * 64 + nb * 16 + fr];
  float* orow = out + (long)(b * 64 + oh) * 64 * 256;
#pragma unroll
  for (int m2 = 0; m2 < 4; ++m2) {
#pragma unroll
    for (int j = 0; j < 4; ++j) {
      const int ow = m2 * 16 + kg * 4 + j;
#pragma unroll
      for (int nb = 0; nb < 4; ++nb)
        orow[ow * 256 + wv * 64 + nb * 16 + fr] = acc[m2][nb][j] + bs[nb];
    }
  }
}

extern "C" void kernel_launch(void* const* d_in, const int* in_sizes, int n_in,
                              void* d_out, int out_size, void* d_ws, size_t ws_size,
                              hipStream_t stream) {
  const float* x    = (const float*)d_in[0];
  const float* off  = (const float*)d_in[1];
  const float* mo   = (const float*)d_in[2];
  const float* kf   = (const float*)d_in[3];
  const float* bias = (const float*)d_in[4];
  float* outp = (float*)d_out;
  unsigned short* wt = (unsigned short*)d_ws;   // 1152*256*2 = 589,824 B

  wt_transpose<<<(KKt * Ff + 255) / 256, 256, 0, stream>>>(kf, wt);
  dcn_main<<<512, 256, 0, stream>>>(x, off, mo, wt, bias, outp);
}

// Round 2
// 83.751 us; speedup vs baseline: 1.5429x; 1.5429x over previous
//
#include <hip/hip_runtime.h>

typedef __attribute__((ext_vector_type(8))) short short8;
typedef __attribute__((ext_vector_type(4))) float f32x4;

__device__ __forceinline__ unsigned short f2bf(float f) {
  union { float f; unsigned u; } v; v.f = f;
  unsigned r = v.u + 0x7FFFu + ((v.u >> 16) & 1u);
  return (unsigned short)(r >> 16);
}

// ---- problem constants ----
// x: (8,64,64,128) f32 ; offset: (8,64,64,18) ; modulation: (8,64,64,9)
// conv_kernel: (3,3,128,256) ; bias: (256,) ; out: (8,64,64,256) f32
// GEMM view: M=32768 (b,oh,ow), K=1152 ((dy*3+dx)*128+c), N=256 (f)
// A[m,kk] = feats[b, (3*oh+dy)%64, ow, ((3*oh+dy)/64)*3+dx, c]
constexpr int KKt = 1152;
constexpr int Ff  = 256;

// Transpose+convert conv_kernel (flat [kk][f] f32) -> Wt [f][kk] bf16 in d_ws.
__global__ void wt_transpose(const float* __restrict__ kf, unsigned short* __restrict__ wt) {
  int idx = blockIdx.x * 256 + threadIdx.x;   // idx = f*KKt + kk
  if (idx >= KKt * Ff) return;
  int f = idx / KKt, kk = idx - f * KKt;
  wt[idx] = f2bf(kf[kk * Ff + f]);
}

__global__ __launch_bounds__(512, 4) void dcn_main(
    const float* __restrict__ x, const float* __restrict__ off,
    const float* __restrict__ mo, const unsigned short* __restrict__ wt,
    const float* __restrict__ bias, float* __restrict__ out) {
  __shared__ unsigned short Asm[64 * 128];     // A-tile chunk, XOR-swizzled, 16 KB

  // XCD-aware mapping: blockIdx%8 selects XCD (round-robin dispatch), so give
  // each XCD exactly one batch image -> its x slice (2.1 MB) stays L2-resident.
  const int b  = blockIdx.x & 7;
  const int oh = blockIdx.x >> 3;
  const int t  = threadIdx.x;
  const int lane = t & 63;
  const int wv   = t >> 6;          // wave 0..7 -> F cols [wv*32, wv*32+32)
  const int fr   = lane & 15;       // fragment row/col within 16
  const int kg   = lane >> 4;       // k-octet group 0..3
  // staging role: 8 threads per output row (ow), 16 channels each
  const int sow = t >> 3;
  const int cb  = (t & 7) << 4;

  f32x4 acc[4][2];
#pragma unroll
  for (int i = 0; i < 4; ++i)
#pragma unroll
    for (int j = 0; j < 2; ++j) acc[i][j] = f32x4{0.f, 0.f, 0.f, 0.f};

  for (int ch = 0; ch < 9; ++ch) {
    const int dy  = ch / 3;
    const int dxk = ch - dy * 3;
    const int r   = 3 * oh + dy;
    const int hp  = r & 63;               // source pixel row h'
    const int kp  = (r >> 6) * 3 + dxk;   // tap index k' in 0..8

    // ---------- stage feats chunk (64 rows x 128 ch) into LDS as bf16 ----------
    {
      const int pix = (b * 64 + hp) * 64 + sow;
      const float oy = off[pix * 18 + kp];
      const float ox = off[pix * 18 + 9 + kp];
      const float mm = mo[pix * 9 + kp];
      // p = offset + (h'+1, ow+1) + (ky, kx), ky=kp/3-1, kx=kp%3-1
      const float py = oy + (float)(hp + kp / 3);
      const float px = ox + (float)(sow + kp % 3);
      const float y0f = floorf(py), x0f = floorf(px);
      const float y0 = fminf(fmaxf(y0f, 0.f), 65.f);
      const float y1 = fminf(fmaxf(y0f + 1.f, 0.f), 65.f);
      const float x0 = fminf(fmaxf(x0f, 0.f), 65.f);
      const float x1 = fminf(fmaxf(x0f + 1.f, 0.f), 65.f);
      const float ly = fminf(fmaxf(py, 0.f), 65.f) - y0;
      const float lx = fminf(fmaxf(px, 0.f), 65.f) - x0;
      // reference's (quirky) weight<->corner pairing, matched exactly:
      float w00 = (1.f - ly) * (1.f - lx) * mm;   // gather(y0,x0)
      float w01 = (1.f - ly) * lx * mm;           // gather(y1,x0)
      float w10 = ly * (1.f - lx) * mm;           // gather(y0,x1)
      float w11 = ly * lx * mm;                   // gather(y1,x1)
      const int iy0 = (int)y0, iy1 = (int)y1, ix0 = (int)x0, ix1 = (int)x1;
      const bool v00 = (iy0 >= 1) & (iy0 <= 64) & (ix0 >= 1) & (ix0 <= 64);
      const bool v01 = (iy1 >= 1) & (iy1 <= 64) & (ix0 >= 1) & (ix0 <= 64);
      const bool v10 = (iy0 >= 1) & (iy0 <= 64) & (ix1 >= 1) & (ix1 <= 64);
      const bool v11 = (iy1 >= 1) & (iy1 <= 64) & (ix1 >= 1) & (ix1 <= 64);
      int o00 = ((b * 64 + iy0 - 1) * 64 + (ix0 - 1)) * 128 + cb;
      int o01 = ((b * 64 + iy1 - 1) * 64 + (ix0 - 1)) * 128 + cb;
      int o10 = ((b * 64 + iy0 - 1) * 64 + (ix1 - 1)) * 128 + cb;
      int o11 = ((b * 64 + iy1 - 1) * 64 + (ix1 - 1)) * 128 + cb;
      if (!v00) { o00 = 0; w00 = 0.f; }
      if (!v01) { o01 = 0; w01 = 0.f; }
      if (!v10) { o10 = 0; w10 = 0.f; }
      if (!v11) { o11 = 0; w11 = 0.f; }
      const f32x4* p00 = (const f32x4*)(x + o00);
      const f32x4* p01 = (const f32x4*)(x + o01);
      const f32x4* p10 = (const f32x4*)(x + o10);
      const f32x4* p11 = (const f32x4*)(x + o11);
      char* lrow = (char*)Asm + sow * 256;
      const int swz = (sow & 7) << 4;
#pragma unroll
      for (int i8 = 0; i8 < 2; ++i8) {
        f32x4 a0 = p00[i8 * 2], a1 = p00[i8 * 2 + 1];
        f32x4 b0 = p01[i8 * 2], b1 = p01[i8 * 2 + 1];
        f32x4 c0 = p10[i8 * 2], c1 = p10[i8 * 2 + 1];
        f32x4 d0 = p11[i8 * 2], d1 = p11[i8 * 2 + 1];
        f32x4 ra = w00 * a0 + w01 * b0 + w10 * c0 + w11 * d0;
        f32x4 rb = w00 * a1 + w01 * b1 + w10 * c1 + w11 * d1;
        short8 pk;
        pk[0] = (short)f2bf(ra.x); pk[1] = (short)f2bf(ra.y);
        pk[2] = (short)f2bf(ra.z); pk[3] = (short)f2bf(ra.w);
        pk[4] = (short)f2bf(rb.x); pk[5] = (short)f2bf(rb.y);
        pk[6] = (short)f2bf(rb.z); pk[7] = (short)f2bf(rb.w);
        *(short8*)(lrow + (((cb << 1) + i8 * 16) ^ swz)) = pk;
      }
    }
    __syncthreads();

    // ---------- GEMM: 4 k-steps of 32 over this 128-chunk ----------
#pragma unroll
    for (int ks = 0; ks < 4; ++ks) {
      short8 af[4], bfr[2];
#pragma unroll
      for (int m2 = 0; m2 < 4; ++m2) {
        const int rw = m2 * 16 + fr;
        af[m2] = *(const short8*)((const char*)Asm + rw * 256 +
                                  ((ks * 64 + kg * 16) ^ ((rw & 7) << 4)));
      }
#pragma unroll
      for (int nb = 0; nb < 2; ++nb) {
        const int f = wv * 32 + nb * 16 + fr;
        bfr[nb] = *(const short8*)(wt + f * KKt + ch * 128 + ks * 32 + kg * 8);
      }
#pragma unroll
      for (int m2 = 0; m2 < 4; ++m2)
#pragma unroll
        for (int nb = 0; nb < 2; ++nb)
          acc[m2][nb] = __builtin_amdgcn_mfma_f32_16x16x32_bf16(af[m2], bfr[nb], acc[m2][nb], 0, 0, 0);
    }
    __syncthreads();
  }

  // ---------- epilogue: D layout col=lane&15, row=(lane>>4)*4+reg ----------
  float bs[2];
#pragma unroll
  for (int nb = 0; nb < 2; ++nb) bs[nb] = bias[wv * 32 + nb * 16 + fr];
  float* orow = out + (long)(b * 64 + oh) * 64 * 256;
#pragma unroll
  for (int m2 = 0; m2 < 4; ++m2) {
#pragma unroll
    for (int j = 0; j < 4; ++j) {
      const int ow = m2 * 16 + kg * 4 + j;
#pragma unroll
      for (int nb = 0; nb < 2; ++nb)
        orow[ow * 256 + wv * 32 + nb * 16 + fr] = acc[m2][nb][j] + bs[nb];
    }
  }
}

extern "C" void kernel_launch(void* const* d_in, const int* in_sizes, int n_in,
                              void* d_out, int out_size, void* d_ws, size_t ws_size,
                              hipStream_t stream) {
  const float* x    = (const float*)d_in[0];
  const float* off  = (const float*)d_in[1];
  const float* mo   = (const float*)d_in[2];
  const float* kf   = (const float*)d_in[3];
  const float* bias = (const float*)d_in[4];
  float* outp = (float*)d_out;
  unsigned short* wt = (unsigned short*)d_ws;   // 1152*256*2 = 589,824 B

  wt_transpose<<<(KKt * Ff + 255) / 256, 256, 0, stream>>>(kf, wt);
  dcn_main<<<512, 512, 0, stream>>>(x, off, mo, wt, bias, outp);
}

// Round 3
// 80.661 us; speedup vs baseline: 1.6020x; 1.0383x over previous
//
#include <hip/hip_runtime.h>

typedef __attribute__((ext_vector_type(8))) short short8;
typedef __attribute__((ext_vector_type(4))) float f32x4;

__device__ __forceinline__ unsigned short f2bf(float f) {
  union { float f; unsigned u; } v; v.f = f;
  unsigned r = v.u + 0x7FFFu + ((v.u >> 16) & 1u);
  return (unsigned short)(r >> 16);
}

__device__ __forceinline__ short8 pack8(f32x4 a, f32x4 b) {
  short8 p;
  p[0] = (short)f2bf(a.x); p[1] = (short)f2bf(a.y);
  p[2] = (short)f2bf(a.z); p[3] = (short)f2bf(a.w);
  p[4] = (short)f2bf(b.x); p[5] = (short)f2bf(b.y);
  p[6] = (short)f2bf(b.z); p[7] = (short)f2bf(b.w);
  return p;
}

// x: (8,64,64,128) f32 ; offset: (8,64,64,18) ; modulation: (8,64,64,9)
// conv_kernel: (3,3,128,256) ; bias: (256,) ; out: (8,64,64,256) f32
// GEMM view: M=32768 (b,oh,ow), K=1152, N=256.
constexpr int KKt = 1152;
constexpr int Ff  = 256;

__global__ void wt_transpose(const float* __restrict__ kf, unsigned short* __restrict__ wt) {
  int idx = blockIdx.x * 256 + threadIdx.x;   // idx = f*KKt + kk
  if (idx >= KKt * Ff) return;
  int f = idx / KKt, kk = idx - f * KKt;
  wt[idx] = f2bf(kf[kk * Ff + f]);
}

__global__ __launch_bounds__(512, 4) void dcn_main(
    const float* __restrict__ x, const float* __restrict__ off,
    const float* __restrict__ mo, const unsigned short* __restrict__ wt,
    const float* __restrict__ bias, float* __restrict__ out) {
  // k-major double-buffered A tile: [buf][k-octet][row][8ch]. Both ds_write
  // and ds_read_b128 are contiguous 1KB wave patterns (bank-floor, no swizzle).
  __shared__ unsigned short Asm[2][16][64][8];

  const int b  = blockIdx.x & 7;      // one batch image per XCD (L2-resident)
  const int oh = blockIdx.x >> 3;
  const int t  = threadIdx.x;
  const int lane = t & 63;
  const int wv   = t >> 6;            // 8 waves -> F cols [wv*32, wv*32+32)
  const int fr   = lane & 15;
  const int kg   = lane >> 4;
  const int sow  = t >> 3;            // staging: 8 threads per output row
  const int c16  = t & 7;             // 16-channel group per thread

  f32x4 acc[4][2];
#pragma unroll
  for (int i = 0; i < 4; ++i) { acc[i][0] = f32x4{0,0,0,0}; acc[i][1] = f32x4{0,0,0,0}; }

  float oyr[2], oxr[2], mmr[2];       // rolling offset regs (slot = ch&1)
  int   og[4]; float wg[4];           // next-chunk gather addrs/weights

  auto loadOff = [&](int ch, int sl) {
    const int dy = ch / 3, dxk = ch - dy * 3;
    const int r = 3 * oh + dy, hp = r & 63, kp = ((r >> 6) * 3) + dxk;
    const int pix = (b * 64 + hp) * 64 + sow;
    oyr[sl] = off[pix * 18 + kp];
    oxr[sl] = off[pix * 18 + 9 + kp];
    mmr[sl] = mo[pix * 9 + kp];
  };

  auto calc = [&](int ch, int sl) {
    const int dy = ch / 3, dxk = ch - dy * 3;
    const int r = 3 * oh + dy, hp = r & 63, kp = ((r >> 6) * 3) + dxk;
    const float py = oyr[sl] + (float)(hp + kp / 3);
    const float px = oxr[sl] + (float)(sow + kp % 3);
    const float mm = mmr[sl];
    const float y0f = floorf(py), x0f = floorf(px);
    const float y0 = fminf(fmaxf(y0f, 0.f), 65.f);
    const float y1 = fminf(fmaxf(y0f + 1.f, 0.f), 65.f);
    const float x0 = fminf(fmaxf(x0f, 0.f), 65.f);
    const float x1 = fminf(fmaxf(x0f + 1.f, 0.f), 65.f);
    const float ly = fminf(fmaxf(py, 0.f), 65.f) - y0;
    const float lx = fminf(fmaxf(px, 0.f), 65.f) - x0;
    // reference's corner<->weight pairing, matched exactly:
    wg[0] = (1.f - ly) * (1.f - lx) * mm;   // (y0,x0)
    wg[1] = (1.f - ly) * lx * mm;           // (y1,x0)
    wg[2] = ly * (1.f - lx) * mm;           // (y0,x1)
    wg[3] = ly * lx * mm;                   // (y1,x1)
    const int iy0 = (int)y0, iy1 = (int)y1, ix0 = (int)x0, ix1 = (int)x1;
    const int yy[4] = {iy0, iy1, iy0, iy1};
    const int xx[4] = {ix0, ix0, ix1, ix1};
#pragma unroll
    for (int j = 0; j < 4; ++j) {
      const bool v = (yy[j] >= 1) & (yy[j] <= 64) & (xx[j] >= 1) & (xx[j] <= 64);
      int o = ((b * 64 + yy[j] - 1) * 64 + (xx[j] - 1)) * 128 + c16 * 16;
      if (!v) { o = 0; wg[j] = 0.f; }
      og[j] = o;
    }
  };

  auto ld4 = [&](int o, f32x4* L) {
    const f32x4* p = (const f32x4*)(x + o);
    L[0] = p[0]; L[1] = p[1]; L[2] = p[2]; L[3] = p[3];
  };

  auto mmah = [&](int buf, int ch, int ks0) {
#pragma unroll
    for (int ks = ks0; ks < ks0 + 2; ++ks) {
      short8 af[4], bfr[2];
#pragma unroll
      for (int m2 = 0; m2 < 4; ++m2)
        af[m2] = *(const short8*)&Asm[buf][ks * 4 + kg][m2 * 16 + fr][0];
#pragma unroll
      for (int nb = 0; nb < 2; ++nb)
        bfr[nb] = *(const short8*)(wt + (wv * 32 + nb * 16 + fr) * KKt +
                                   ch * 128 + ks * 32 + kg * 8);
#pragma unroll
      for (int m2 = 0; m2 < 4; ++m2)
#pragma unroll
        for (int nb = 0; nb < 2; ++nb)
          acc[m2][nb] = __builtin_amdgcn_mfma_f32_16x16x32_bf16(af[m2], bfr[nb], acc[m2][nb], 0, 0, 0);
    }
  };

  f32x4 A[4], B[4], C[4], D[4];

  // ---- prologue: stage chunk 0 into buf0, preload offsets for ch1 ----
  loadOff(0, 0);
  loadOff(1, 1);
  calc(0, 0);
  ld4(og[0], A); ld4(og[1], B); ld4(og[2], C); ld4(og[3], D);
  {
    f32x4 r0 = wg[0] * A[0] + wg[1] * B[0] + wg[2] * C[0] + wg[3] * D[0];
    f32x4 r1 = wg[0] * A[1] + wg[1] * B[1] + wg[2] * C[1] + wg[3] * D[1];
    f32x4 r2 = wg[0] * A[2] + wg[1] * B[2] + wg[2] * C[2] + wg[3] * D[2];
    f32x4 r3 = wg[0] * A[3] + wg[1] * B[3] + wg[2] * C[3] + wg[3] * D[3];
    *(short8*)&Asm[0][2 * c16][sow][0]     = pack8(r0, r1);
    *(short8*)&Asm[0][2 * c16 + 1][sow][0] = pack8(r2, r3);
  }
  __syncthreads();

  // ---- pipelined main loop: 1 barrier per chunk ----
#pragma unroll
  for (int ch = 0; ch < 9; ++ch) {
    const int buf = ch & 1;
    f32x4 P0, P1, P2, P3;
    if (ch < 8) {
      calc(ch + 1, (ch + 1) & 1);       // offsets were loaded last iteration
      ld4(og[0], A); ld4(og[1], B);     // batch 1: corners (y0,x0),(y1,x0)
    }
    mmah(buf, ch, 0);                   // MFMA ks=0,1 hides batch-1 latency
    if (ch < 8) {
      P0 = wg[0] * A[0] + wg[1] * B[0];
      P1 = wg[0] * A[1] + wg[1] * B[1];
      P2 = wg[0] * A[2] + wg[1] * B[2];
      P3 = wg[0] * A[3] + wg[1] * B[3];
      ld4(og[2], C); ld4(og[3], D);     // batch 2: corners (y0,x1),(y1,x1)
    }
    if (ch < 7) loadOff(ch + 2, ch & 1);
    mmah(buf, ch, 2);                   // MFMA ks=2,3 hides batch-2 latency
    if (ch < 8) {
      P0 += wg[2] * C[0] + wg[3] * D[0];
      P1 += wg[2] * C[1] + wg[3] * D[1];
      P2 += wg[2] * C[2] + wg[3] * D[2];
      P3 += wg[2] * C[3] + wg[3] * D[3];
      *(short8*)&Asm[buf ^ 1][2 * c16][sow][0]     = pack8(P0, P1);
      *(short8*)&Asm[buf ^ 1][2 * c16 + 1][sow][0] = pack8(P2, P3);
    }
    __syncthreads();
  }

  // ---- epilogue: D layout col=lane&15, row=(lane>>4)*4+reg ----
  float bs[2];
#pragma unroll
  for (int nb = 0; nb < 2; ++nb) bs[nb] = bias[wv * 32 + nb * 16 + fr];
  float* orow = out + (long)(b * 64 + oh) * 64 * 256;
#pragma unroll
  for (int m2 = 0; m2 < 4; ++m2) {
#pragma unroll
    for (int j = 0; j < 4; ++j) {
      const int ow = m2 * 16 + kg * 4 + j;
#pragma unroll
      for (int nb = 0; nb < 2; ++nb)
        orow[ow * 256 + wv * 32 + nb * 16 + fr] = acc[m2][nb][j] + bs[nb];
    }
  }
}

extern "C" void kernel_launch(void* const* d_in, const int* in_sizes, int n_in,
                              void* d_out, int out_size, void* d_ws, size_t ws_size,
                              hipStream_t stream) {
  const float* x    = (const float*)d_in[0];
  const float* off  = (const float*)d_in[1];
  const float* mo   = (const float*)d_in[2];
  const float* kf   = (const float*)d_in[3];
  const float* bias = (const float*)d_in[4];
  float* outp = (float*)d_out;
  unsigned short* wt = (unsigned short*)d_ws;   // 1152*256*2 = 589,824 B

  wt_transpose<<<(KKt * Ff + 255) / 256, 256, 0, stream>>>(kf, wt);
  dcn_main<<<512, 512, 0, stream>>>(x, off, mo, wt, bias, outp);
}

// Round 4
// 74.158 us; speedup vs baseline: 1.7424x; 1.0877x over previous
//
#include <hip/hip_runtime.h>

typedef __attribute__((ext_vector_type(8))) short short8;
typedef __attribute__((ext_vector_type(4))) float f32x4;

__device__ __forceinline__ unsigned short f2bf(float f) {
  union { float f; unsigned u; } v; v.f = f;
  unsigned r = v.u + 0x7FFFu + ((v.u >> 16) & 1u);
  return (unsigned short)(r >> 16);
}

__device__ __forceinline__ short8 pack8(f32x4 a, f32x4 b) {
  short8 p;
  p[0] = (short)f2bf(a.x); p[1] = (short)f2bf(a.y);
  p[2] = (short)f2bf(a.z); p[3] = (short)f2bf(a.w);
  p[4] = (short)f2bf(b.x); p[5] = (short)f2bf(b.y);
  p[6] = (short)f2bf(b.z); p[7] = (short)f2bf(b.w);
  return p;
}

// x: (8,64,64,128) f32 ; offset: (8,64,64,18) ; modulation: (8,64,64,9)
// conv_kernel: (3,3,128,256) ; bias: (256,) ; out: (8,64,64,256) f32
// GEMM view: M=32768 (b,oh,ow), K=1152, N=256.
constexpr int KKt = 1152;
constexpr int Ff  = 256;

__global__ void wt_transpose(const float* __restrict__ kf, unsigned short* __restrict__ wt) {
  int idx = blockIdx.x * 256 + threadIdx.x;   // idx = f*KKt + kk
  if (idx >= KKt * Ff) return;
  int f = idx / KKt, kk = idx - f * KKt;
  wt[idx] = f2bf(kf[kk * Ff + f]);
}

// 512 blocks x 1024 threads (16 waves). 2 blocks/CU x 16 waves = 32 waves/CU
// (100% occupancy cap) -> VGPR budget 64, hence lean acc[4] (16-wide F slice).
__global__ __launch_bounds__(1024, 8) void dcn_main(
    const float* __restrict__ x, const float* __restrict__ off,
    const float* __restrict__ mo, const unsigned short* __restrict__ wt,
    const float* __restrict__ bias, float* __restrict__ out) {
  // Row-major [row][128ch] bf16, XOR-swizzled 16B chunks (R2-proven layout).
  __shared__ unsigned short Asm[2][64][128];   // 2 x 16 KB

  const int b  = blockIdx.x & 7;      // one batch image per XCD (L2-resident)
  const int oh = blockIdx.x >> 3;
  const int t  = threadIdx.x;
  const int lane = t & 63;
  const int wv   = t >> 6;            // 16 waves -> F cols [wv*16, wv*16+16)
  const int fr   = lane & 15;
  const int kg   = lane >> 4;
  const int sow  = t >> 4;            // staging: 16 threads per output row
  const int c8   = t & 15;            // 8-channel group per thread

  f32x4 acc[4];
#pragma unroll
  for (int i = 0; i < 4; ++i) acc[i] = f32x4{0.f, 0.f, 0.f, 0.f};

  float oyr[2], oxr[2], mmr[2];       // rolling offset regs (slot = ch&1)
  int   og[4]; float wg[4];           // current-stage gather addrs/weights

  auto loadOff = [&](int ch, int sl) {
    const int dy = ch / 3, dxk = ch - dy * 3;
    const int r = 3 * oh + dy, hp = r & 63, kp = ((r >> 6) * 3) + dxk;
    const int pix = (b * 64 + hp) * 64 + sow;
    oyr[sl] = off[pix * 18 + kp];
    oxr[sl] = off[pix * 18 + 9 + kp];
    mmr[sl] = mo[pix * 9 + kp];
  };

  auto calc = [&](int ch, int sl) {
    const int dy = ch / 3, dxk = ch - dy * 3;
    const int r = 3 * oh + dy, hp = r & 63, kp = ((r >> 6) * 3) + dxk;
    const float py = oyr[sl] + (float)(hp + kp / 3);
    const float px = oxr[sl] + (float)(sow + kp % 3);
    const float mm = mmr[sl];
    const float y0f = floorf(py), x0f = floorf(px);
    const float y0 = fminf(fmaxf(y0f, 0.f), 65.f);
    const float y1 = fminf(fmaxf(y0f + 1.f, 0.f), 65.f);
    const float x0 = fminf(fmaxf(x0f, 0.f), 65.f);
    const float x1 = fminf(fmaxf(x0f + 1.f, 0.f), 65.f);
    const float ly = fminf(fmaxf(py, 0.f), 65.f) - y0;
    const float lx = fminf(fmaxf(px, 0.f), 65.f) - x0;
    // reference's corner<->weight pairing, matched exactly:
    wg[0] = (1.f - ly) * (1.f - lx) * mm;   // (y0,x0)
    wg[1] = (1.f - ly) * lx * mm;           // (y1,x0)
    wg[2] = ly * (1.f - lx) * mm;           // (y0,x1)
    wg[3] = ly * lx * mm;                   // (y1,x1)
    const int iy0 = (int)y0, iy1 = (int)y1, ix0 = (int)x0, ix1 = (int)x1;
    const int yy[4] = {iy0, iy1, iy0, iy1};
    const int xx[4] = {ix0, ix0, ix1, ix1};
#pragma unroll
    for (int j = 0; j < 4; ++j) {
      const bool v = (yy[j] >= 1) & (yy[j] <= 64) & (xx[j] >= 1) & (xx[j] <= 64);
      int o = ((b * 64 + yy[j] - 1) * 64 + (xx[j] - 1)) * 128 + c8 * 8;
      if (!v) { o = 0; wg[j] = 0.f; }
      og[j] = o;
    }
  };

  auto mmah = [&](int buf, int ch, int ks0) {
#pragma unroll
    for (int ks = ks0; ks < ks0 + 2; ++ks) {
      short8 af[4], bfr;
#pragma unroll
      for (int m2 = 0; m2 < 4; ++m2) {
        const int rw = m2 * 16 + fr;
        af[m2] = *(const short8*)((const char*)&Asm[buf][0][0] + rw * 256 +
                                  ((ks * 64 + kg * 16) ^ ((rw & 7) << 4)));
      }
      bfr = *(const short8*)(wt + (wv * 16 + fr) * KKt + ch * 128 + ks * 32 + kg * 8);
#pragma unroll
      for (int m2 = 0; m2 < 4; ++m2)
        acc[m2] = __builtin_amdgcn_mfma_f32_16x16x32_bf16(af[m2], bfr, acc[m2], 0, 0, 0);
    }
  };

  const int wbyte = sow * 256 + ((c8 * 16) ^ ((sow & 7) << 4));

  // ---- prologue: stage chunk 0 into buf0 ----
  loadOff(0, 0);
  loadOff(1, 1);
  calc(0, 0);
  {
    const f32x4* p0 = (const f32x4*)(x + og[0]);
    const f32x4* p1 = (const f32x4*)(x + og[1]);
    f32x4 E0 = p0[0], E1 = p0[1], E2 = p1[0], E3 = p1[1];
    f32x4 P0 = wg[0] * E0 + wg[1] * E2;
    f32x4 P1 = wg[0] * E1 + wg[1] * E3;
    const f32x4* p2 = (const f32x4*)(x + og[2]);
    const f32x4* p3 = (const f32x4*)(x + og[3]);
    f32x4 F0 = p2[0], F1 = p2[1], F2 = p3[0], F3 = p3[1];
    P0 += wg[2] * F0 + wg[3] * F2;
    P1 += wg[2] * F1 + wg[3] * F3;
    *(short8*)((char*)&Asm[0][0][0] + wbyte) = pack8(P0, P1);
  }
  __syncthreads();

  // ---- pipelined main loop: 1 barrier per chunk ----
#pragma unroll
  for (int ch = 0; ch < 9; ++ch) {
    const int buf = ch & 1;
    f32x4 E0, E1, E2, E3, P0, P1;
    if (ch < 8) {
      calc(ch + 1, (ch + 1) & 1);       // offsets were loaded last iteration
      const f32x4* p0 = (const f32x4*)(x + og[0]);
      const f32x4* p1 = (const f32x4*)(x + og[1]);
      E0 = p0[0]; E1 = p0[1]; E2 = p1[0]; E3 = p1[1];   // corners (y0,x0),(y1,x0)
    }
    mmah(buf, ch, 0);                   // MFMA ks=0,1 hides corner-pair-1 latency
    if (ch < 8) {
      P0 = wg[0] * E0 + wg[1] * E2;
      P1 = wg[0] * E1 + wg[1] * E3;
      const f32x4* p2 = (const f32x4*)(x + og[2]);
      const f32x4* p3 = (const f32x4*)(x + og[3]);
      E0 = p2[0]; E1 = p2[1]; E2 = p3[0]; E3 = p3[1];   // corners (y0,x1),(y1,x1)
    }
    if (ch < 7) loadOff(ch + 2, ch & 1);
    mmah(buf, ch, 2);                   // MFMA ks=2,3 hides corner-pair-2 latency
    if (ch < 8) {
      P0 += wg[2] * E0 + wg[3] * E2;
      P1 += wg[2] * E1 + wg[3] * E3;
      *(short8*)((char*)&Asm[buf ^ 1][0][0] + wbyte) = pack8(P0, P1);
    }
    __syncthreads();
  }

  // ---- epilogue: D layout col=lane&15, row=(lane>>4)*4+reg ----
  const float bs = bias[wv * 16 + fr];
  float* orow = out + (long)(b * 64 + oh) * 64 * 256;
#pragma unroll
  for (int m2 = 0; m2 < 4; ++m2) {
#pragma unroll
    for (int j = 0; j < 4; ++j) {
      const int ow = m2 * 16 + kg * 4 + j;
      orow[ow * 256 + wv * 16 + fr] = acc[m2][j] + bs;
    }
  }
}

extern "C" void kernel_launch(void* const* d_in, const int* in_sizes, int n_in,
                              void* d_out, int out_size, void* d_ws, size_t ws_size,
                              hipStream_t stream) {
  const float* x    = (const float*)d_in[0];
  const float* off  = (const float*)d_in[1];
  const float* mo   = (const float*)d_in[2];
  const float* kf   = (const float*)d_in[3];
  const float* bias = (const float*)d_in[4];
  float* outp = (float*)d_out;
  unsigned short* wt = (unsigned short*)d_ws;   // 1152*256*2 = 589,824 B

  wt_transpose<<<(KKt * Ff + 255) / 256, 256, 0, stream>>>(kf, wt);
  dcn_main<<<512, 1024, 0, stream>>>(x, off, mo, wt, bias, outp);
}

// Round 5
// 58.678 us; speedup vs baseline: 2.2021x; 1.2638x over previous
//
#include <hip/hip_runtime.h>

typedef __attribute__((ext_vector_type(8))) short short8;
typedef __attribute__((ext_vector_type(4))) float f32x4;

__device__ __forceinline__ unsigned short f2bf(float f) {
  union { float f; unsigned u; } v; v.f = f;
  unsigned r = v.u + 0x7FFFu + ((v.u >> 16) & 1u);
  return (unsigned short)(r >> 16);
}

__device__ __forceinline__ short8 pack8(f32x4 a, f32x4 b) {
  short8 p;
  p[0] = (short)f2bf(a.x); p[1] = (short)f2bf(a.y);
  p[2] = (short)f2bf(a.z); p[3] = (short)f2bf(a.w);
  p[4] = (short)f2bf(b.x); p[5] = (short)f2bf(b.y);
  p[6] = (short)f2bf(b.z); p[7] = (short)f2bf(b.w);
  return p;
}

// x: (8,64,64,128) f32 ; offset: (8,64,64,18) ; modulation: (8,64,64,9)
// conv_kernel: (3,3,128,256) ; bias: (256,) ; out: (8,64,64,256) f32
constexpr int KKt = 1152;
constexpr int Ff  = 256;

// wtB fragment-major: idx = ((((ch*4+ks)*16+ft)*4+kg)*16+fr)*8+j holds
// element (f = ft*16+fr, k = ch*128+ks*32+kg*8+j). A wave's B-fragment load
// is then lane-contiguous (1 KB per (ch,ks,ft)).
__global__ void wt_prep(const float* __restrict__ kf, unsigned short* __restrict__ wtB) {
  int idx = blockIdx.x * 256 + threadIdx.x;   // 294912 = 1152*256 exact
  int j  = idx & 7;
  int fr = (idx >> 3) & 15;
  int kg = (idx >> 7) & 3;
  int ft = (idx >> 9) & 15;
  int ks = (idx >> 13) & 3;
  int ch = idx >> 15;
  int k = ch * 128 + ks * 32 + kg * 8 + j;
  int f = ft * 16 + fr;
  wtB[idx] = f2bf(kf[k * Ff + f]);
}

// 512 blocks x 512 threads (8 waves). Wave wv covers F-slice [wv*32, wv*32+32).
__global__ __launch_bounds__(512, 4) void dcn_main(
    const float* __restrict__ x, const float* __restrict__ off,
    const float* __restrict__ mo, const unsigned short* __restrict__ wtB,
    const float* __restrict__ bias, float* __restrict__ out) {
  // A tile, row stride 272 B (+16B pad): conflict-free on both ds_write_b128
  // (bank start 4r+8c mod 32, uniform) and af ds_read_b128 (4r+16ks+4kg, uniform).
  __shared__ __align__(16) char At[2][64 * 272];

  const int b  = blockIdx.x & 7;      // one batch image per XCD (L2-resident)
  const int oh = blockIdx.x >> 3;
  const int t  = threadIdx.x;
  const int lane = t & 63;
  const int wv   = t >> 6;
  const int fr   = lane & 15;
  const int kg   = lane >> 4;
  const int sow  = t >> 3;            // staging: 8 threads per row
  const int c16  = t & 7;             // 16-channel group

  f32x4 acc[4][2];
#pragma unroll
  for (int i = 0; i < 4; ++i) { acc[i][0] = f32x4{0,0,0,0}; acc[i][1] = f32x4{0,0,0,0}; }

  float oyr[2], oxr[2], mmr[2];
  int   og[4]; float wg[4];

  auto loadOff = [&](int ch, int sl) {
    const int dy = ch / 3, dxk = ch - dy * 3;
    const int r = 3 * oh + dy, hp = r & 63, kp = ((r >> 6) * 3) + dxk;
    const int pix = (b * 64 + hp) * 64 + sow;
    oyr[sl] = off[pix * 18 + kp];
    oxr[sl] = off[pix * 18 + 9 + kp];
    mmr[sl] = mo[pix * 9 + kp];
  };

  auto calcW = [&](int ch, int sl) {
    const int dy = ch / 3, dxk = ch - dy * 3;
    const int r = 3 * oh + dy, hp = r & 63, kp = ((r >> 6) * 3) + dxk;
    const float py = oyr[sl] + (float)(hp + kp / 3);
    const float px = oxr[sl] + (float)(sow + kp % 3);
    const float mm = mmr[sl];
    const float y0f = floorf(py), x0f = floorf(px);
    const float y0 = fminf(fmaxf(y0f, 0.f), 65.f);
    const float y1 = fminf(fmaxf(y0f + 1.f, 0.f), 65.f);
    const float x0 = fminf(fmaxf(x0f, 0.f), 65.f);
    const float x1 = fminf(fmaxf(x0f + 1.f, 0.f), 65.f);
    const float ly = fminf(fmaxf(py, 0.f), 65.f) - y0;
    const float lx = fminf(fmaxf(px, 0.f), 65.f) - x0;
    // reference's corner<->weight pairing, matched exactly:
    wg[0] = (1.f - ly) * (1.f - lx) * mm;   // (y0,x0)
    wg[1] = (1.f - ly) * lx * mm;           // (y1,x0)
    wg[2] = ly * (1.f - lx) * mm;           // (y0,x1)
    wg[3] = ly * lx * mm;                   // (y1,x1)
    const int iy0 = (int)y0, iy1 = (int)y1, ix0 = (int)x0, ix1 = (int)x1;
    const int yy[4] = {iy0, iy1, iy0, iy1};
    const int xx[4] = {ix0, ix0, ix1, ix1};
#pragma unroll
    for (int j = 0; j < 4; ++j) {
      const bool v = (yy[j] >= 1) & (yy[j] <= 64) & (xx[j] >= 1) & (xx[j] <= 64);
      int o = ((b * 64 + yy[j] - 1) * 64 + (xx[j] - 1)) * 128 + c16 * 16;
      if (!v) { o = 0; wg[j] = 0.f; }
      og[j] = o;
    }
  };

  auto ldC = [&](int c, f32x4* G) {       // one corner: 4x dwordx4 (16 ch)
    const f32x4* p = (const f32x4*)(x + og[c]);
    G[0] = p[0]; G[1] = p[1]; G[2] = p[2]; G[3] = p[3];
  };

  auto ldB = [&](int ch, int ks, short8* bf) {
    const unsigned short* p = wtB + (((ch * 4 + ks) * 16 + wv * 2) * 64 + lane) * 8;
    bf[0] = *(const short8*)p;
    bf[1] = *(const short8*)(p + 512);
  };

  auto mmah = [&](int buf, int ks, const short8* bf) {
    short8 af[4];
#pragma unroll
    for (int m2 = 0; m2 < 4; ++m2)
      af[m2] = *(const short8*)(At[buf] + (m2 * 16 + fr) * 272 + ks * 64 + kg * 16);
#pragma unroll
    for (int m2 = 0; m2 < 4; ++m2)
#pragma unroll
      for (int nb = 0; nb < 2; ++nb)
        acc[m2][nb] = __builtin_amdgcn_mfma_f32_16x16x32_bf16(af[m2], bf[nb], acc[m2][nb], 0, 0, 0);
  };

  const int wb = sow * 272 + c16 * 32;

  // ---- prologue: stage chunk 0 ----
  loadOff(0, 0); loadOff(1, 1);
  calcW(0, 0);
  {
    f32x4 G0[4], G1[4];
    ldC(0, G0); ldC(1, G1);
    f32x4 P0 = wg[0]*G0[0] + wg[1]*G1[0], P1 = wg[0]*G0[1] + wg[1]*G1[1];
    f32x4 P2 = wg[0]*G0[2] + wg[1]*G1[2], P3 = wg[0]*G0[3] + wg[1]*G1[3];
    ldC(2, G0); ldC(3, G1);
    P0 += wg[2]*G0[0] + wg[3]*G1[0]; P1 += wg[2]*G0[1] + wg[3]*G1[1];
    P2 += wg[2]*G0[2] + wg[3]*G1[2]; P3 += wg[2]*G0[3] + wg[3]*G1[3];
    *(short8*)(At[0] + wb)      = pack8(P0, P1);
    *(short8*)(At[0] + wb + 16) = pack8(P2, P3);
  }
  __syncthreads();

  // ---- main loop: corner-granularity pipeline, 1 barrier per chunk ----
#pragma unroll
  for (int ch = 0; ch < 9; ++ch) {
    const int buf = ch & 1;
    const bool hv = ch < 8;
    if (hv) calcW(ch + 1, (ch + 1) & 1);
    short8 bA[2], bB[2];
    f32x4 G0[4], G1[4], P0, P1, P2, P3;
    ldB(ch, 0, bA);
    // ks 0: issue corner0, compute, combine corner0
    if (hv) ldC(0, G0);
    ldB(ch, 1, bB);
    mmah(buf, 0, bA);
    if (hv) { P0 = wg[0]*G0[0]; P1 = wg[0]*G0[1]; P2 = wg[0]*G0[2]; P3 = wg[0]*G0[3]; }
    // ks 1
    if (hv) ldC(1, G1);
    ldB(ch, 2, bA);
    mmah(buf, 1, bB);
    if (hv) { P0 += wg[1]*G1[0]; P1 += wg[1]*G1[1]; P2 += wg[1]*G1[2]; P3 += wg[1]*G1[3]; }
    // ks 2
    if (hv) ldC(2, G0);
    ldB(ch, 3, bB);
    if (ch < 7) loadOff(ch + 2, ch & 1);
    mmah(buf, 2, bA);
    if (hv) { P0 += wg[2]*G0[0]; P1 += wg[2]*G0[1]; P2 += wg[2]*G0[2]; P3 += wg[2]*G0[3]; }
    // ks 3
    if (hv) ldC(3, G1);
    mmah(buf, 3, bB);
    if (hv) {
      P0 += wg[3]*G1[0]; P1 += wg[3]*G1[1]; P2 += wg[3]*G1[2]; P3 += wg[3]*G1[3];
      *(short8*)(At[buf ^ 1] + wb)      = pack8(P0, P1);
      *(short8*)(At[buf ^ 1] + wb + 16) = pack8(P2, P3);
      __syncthreads();
    }
  }

  // ---- epilogue: D layout col(F)=lane&15, row(M)=(lane>>4)*4+reg ----
  float bs[2];
#pragma unroll
  for (int nb = 0; nb < 2; ++nb) bs[nb] = bias[wv * 32 + nb * 16 + fr];
  float* orow = out + (long)(b * 64 + oh) * 64 * 256;
#pragma unroll
  for (int m2 = 0; m2 < 4; ++m2) {
#pragma unroll
    for (int j = 0; j < 4; ++j) {
      const int ow = m2 * 16 + kg * 4 + j;
#pragma unroll
      for (int nb = 0; nb < 2; ++nb)
        orow[ow * 256 + wv * 32 + nb * 16 + fr] = acc[m2][nb][j] + bs[nb];
    }
  }
}

extern "C" void kernel_launch(void* const* d_in, const int* in_sizes, int n_in,
                              void* d_out, int out_size, void* d_ws, size_t ws_size,
                              hipStream_t stream) {
  const float* x    = (const float*)d_in[0];
  const float* off  = (const float*)d_in[1];
  const float* mo   = (const float*)d_in[2];
  const float* kf   = (const float*)d_in[3];
  const float* bias = (const float*)d_in[4];
  float* outp = (float*)d_out;
  unsigned short* wtB = (unsigned short*)d_ws;   // 1152*256*2 = 589,824 B

  wt_prep<<<1152, 256, 0, stream>>>(kf, wtB);
  dcn_main<<<512, 512, 0, stream>>>(x, off, mo, wtB, bias, outp);
}

// Round 6
// 51.470 us; speedup vs baseline: 2.5105x; 1.1401x over previous
//
#include <hip/hip_runtime.h>

typedef __attribute__((ext_vector_type(8))) short short8;
typedef __attribute__((ext_vector_type(4))) float f32x4;

__device__ __forceinline__ unsigned short f2bf(float f) {
  union { float f; unsigned u; } v; v.f = f;
  unsigned r = v.u + 0x7FFFu + ((v.u >> 16) & 1u);
  return (unsigned short)(r >> 16);
}

__device__ __forceinline__ short8 pack8(f32x4 a, f32x4 b) {
  short8 p;
  p[0] = (short)f2bf(a.x); p[1] = (short)f2bf(a.y);
  p[2] = (short)f2bf(a.z); p[3] = (short)f2bf(a.w);
  p[4] = (short)f2bf(b.x); p[5] = (short)f2bf(b.y);
  p[6] = (short)f2bf(b.z); p[7] = (short)f2bf(b.w);
  return p;
}

// x: (8,64,64,128) f32 ; offset: (8,64,64,18) ; modulation: (8,64,64,9)
// conv_kernel: (3,3,128,256) ; bias: (256,) ; out: (8,64,64,256) f32
constexpr int KKt = 1152;
constexpr int Ff  = 256;
constexpr size_t WT_BYTES = (size_t)KKt * Ff * 2;          // 589,824
constexpr size_t XB_BYTES = (size_t)8 * 64 * 64 * 128 * 2; // 8,388,608

// wtB fragment-major: idx = ((((ch*4+ks)*16+ft)*4+kg)*16+fr)*8+j holds
// element (f = ft*16+fr, k = ch*128+ks*32+kg*8+j): wave B-load is lane-contiguous.
__global__ void wt_prep(const float* __restrict__ kf, unsigned short* __restrict__ wtB) {
  int idx = blockIdx.x * 256 + threadIdx.x;   // 294912 = 1152*256 exact
  int j  = idx & 7;
  int fr = (idx >> 3) & 15;
  int kg = (idx >> 7) & 3;
  int ft = (idx >> 9) & 15;
  int ks = (idx >> 13) & 3;
  int ch = idx >> 15;
  int k = ch * 128 + ks * 32 + kg * 8 + j;
  int f = ft * 16 + fr;
  wtB[idx] = f2bf(kf[k * Ff + f]);
}

// x f32 -> bf16 (halves gather traffic; x is N(0,1), bf16 relerr ~0.4%)
__global__ void x_prep(const float* __restrict__ x, unsigned short* __restrict__ xb) {
  int i = (blockIdx.x * 512 + threadIdx.x) * 8;
  const f32x4* p = (const f32x4*)(x + i);
  *(short8*)(xb + i) = pack8(p[0], p[1]);
}

// 512 blocks x 512 threads (8 waves). Wave wv covers F-slice [wv*32, wv*32+32).
template <bool BX>
__global__ __launch_bounds__(512, 4) void dcn_main(
    const void* __restrict__ xsrc, const float* __restrict__ off,
    const float* __restrict__ mo, const unsigned short* __restrict__ wtB,
    const float* __restrict__ bias, float* __restrict__ out) {
  // A tile, row stride 272 B (+16B pad): uniform bank spread on ds_write_b128
  // and af ds_read_b128.
  __shared__ __align__(16) char At[2][64 * 272];

  const int b  = blockIdx.x & 7;      // one batch image per XCD (L2-resident)
  const int oh = blockIdx.x >> 3;
  const int t  = threadIdx.x;
  const int lane = t & 63;
  const int wv   = t >> 6;
  const int fr   = lane & 15;
  const int kg   = lane >> 4;
  const int sow  = t >> 3;            // staging: 8 threads per row
  const int c16  = t & 7;             // 16-channel group

  f32x4 acc[4][2];
#pragma unroll
  for (int i = 0; i < 4; ++i) { acc[i][0] = f32x4{0,0,0,0}; acc[i][1] = f32x4{0,0,0,0}; }

  float oyr[2], oxr[2], mmr[2];
  int   og[4]; float wg[4];

  auto loadOff = [&](int ch, int sl) {
    const int dy = ch / 3, dxk = ch - dy * 3;
    const int r = 3 * oh + dy, hp = r & 63, kp = ((r >> 6) * 3) + dxk;
    const int pix = (b * 64 + hp) * 64 + sow;
    oyr[sl] = off[pix * 18 + kp];
    oxr[sl] = off[pix * 18 + 9 + kp];
    mmr[sl] = mo[pix * 9 + kp];
  };

  auto calcW = [&](int ch, int sl) {
    const int dy = ch / 3, dxk = ch - dy * 3;
    const int r = 3 * oh + dy, hp = r & 63, kp = ((r >> 6) * 3) + dxk;
    const float py = oyr[sl] + (float)(hp + kp / 3);
    const float px = oxr[sl] + (float)(sow + kp % 3);
    const float mm = mmr[sl];
    const float y0f = floorf(py), x0f = floorf(px);
    const float y0 = fminf(fmaxf(y0f, 0.f), 65.f);
    const float y1 = fminf(fmaxf(y0f + 1.f, 0.f), 65.f);
    const float x0 = fminf(fmaxf(x0f, 0.f), 65.f);
    const float x1 = fminf(fmaxf(x0f + 1.f, 0.f), 65.f);
    const float ly = fminf(fmaxf(py, 0.f), 65.f) - y0;
    const float lx = fminf(fmaxf(px, 0.f), 65.f) - x0;
    // reference's corner<->weight pairing, matched exactly:
    wg[0] = (1.f - ly) * (1.f - lx) * mm;   // (y0,x0)
    wg[1] = (1.f - ly) * lx * mm;           // (y1,x0)
    wg[2] = ly * (1.f - lx) * mm;           // (y0,x1)
    wg[3] = ly * lx * mm;                   // (y1,x1)
    const int iy0 = (int)y0, iy1 = (int)y1, ix0 = (int)x0, ix1 = (int)x1;
    const int yy[4] = {iy0, iy1, iy0, iy1};
    const int xx[4] = {ix0, ix0, ix1, ix1};
#pragma unroll
    for (int j = 0; j < 4; ++j) {
      const bool v = (yy[j] >= 1) & (yy[j] <= 64) & (xx[j] >= 1) & (xx[j] <= 64);
      int o = ((b * 64 + yy[j] - 1) * 64 + (xx[j] - 1)) * 128 + c16 * 16;
      if (!v) { o = 0; wg[j] = 0.f; }
      og[j] = o;
    }
  };

  auto ldB = [&](int ch, int ks, short8* bf) {
    const unsigned short* p = wtB + (((ch * 4 + ks) * 16 + wv * 2) * 64 + lane) * 8;
    bf[0] = *(const short8*)p;
    bf[1] = *(const short8*)(p + 512);
  };

  auto mmah = [&](int buf, int ks, const short8* bf) {
    short8 af[4];
#pragma unroll
    for (int m2 = 0; m2 < 4; ++m2)
      af[m2] = *(const short8*)(At[buf] + (m2 * 16 + fr) * 272 + ks * 64 + kg * 16);
#pragma unroll
    for (int m2 = 0; m2 < 4; ++m2)
#pragma unroll
      for (int nb = 0; nb < 2; ++nb)
        acc[m2][nb] = __builtin_amdgcn_mfma_f32_16x16x32_bf16(af[m2], bf[nb], acc[m2][nb], 0, 0, 0);
  };

  const int wb = sow * 272 + c16 * 32;

  if constexpr (BX) {
    const unsigned short* xb = (const unsigned short*)xsrc;
    auto ldQ = [&](int c, short8* q) {       // one corner: 16 bf16 ch = 2 b128
      const short8* p = (const short8*)(xb + og[c]);
      q[0] = p[0]; q[1] = p[1];
    };
    // accumulate corner (even/odd-deinterleaved f32)
    auto accQ = [&](short8 s, float w, f32x4& Pe, f32x4& Po) {
      union { short8 s; unsigned u[4]; } v; v.s = s;
#pragma unroll
      for (int i = 0; i < 4; ++i) {
        union { unsigned u; float f; } e, o;
        e.u = v.u[i] << 16;
        o.u = v.u[i] & 0xffff0000u;
        Pe[i] = fmaf(w, e.f, Pe[i]);
        Po[i] = fmaf(w, o.f, Po[i]);
      }
    };

    // ---- prologue: stage chunk 0 ----
    loadOff(0, 0); loadOff(1, 1);
    calcW(0, 0);
    {
      short8 q0[2], q1[2], q2[2], q3[2];
      ldQ(0, q0); ldQ(1, q1); ldQ(2, q2); ldQ(3, q3);
      f32x4 Pe0{0,0,0,0}, Po0{0,0,0,0}, Pe1{0,0,0,0}, Po1{0,0,0,0};
      accQ(q0[0], wg[0], Pe0, Po0); accQ(q0[1], wg[0], Pe1, Po1);
      accQ(q1[0], wg[1], Pe0, Po0); accQ(q1[1], wg[1], Pe1, Po1);
      accQ(q2[0], wg[2], Pe0, Po0); accQ(q2[1], wg[2], Pe1, Po1);
      accQ(q3[0], wg[3], Pe0, Po0); accQ(q3[1], wg[3], Pe1, Po1);
      short8 s0, s1;
      s0[0]=f2bf(Pe0.x); s0[1]=f2bf(Po0.x); s0[2]=f2bf(Pe0.y); s0[3]=f2bf(Po0.y);
      s0[4]=f2bf(Pe0.z); s0[5]=f2bf(Po0.z); s0[6]=f2bf(Pe0.w); s0[7]=f2bf(Po0.w);
      s1[0]=f2bf(Pe1.x); s1[1]=f2bf(Po1.x); s1[2]=f2bf(Pe1.y); s1[3]=f2bf(Po1.y);
      s1[4]=f2bf(Pe1.z); s1[5]=f2bf(Po1.z); s1[6]=f2bf(Pe1.w); s1[7]=f2bf(Po1.w);
      *(short8*)(At[0] + wb)      = s0;
      *(short8*)(At[0] + wb + 16) = s1;
    }
    __syncthreads();

    // ---- main loop ----
#pragma unroll
    for (int ch = 0; ch < 9; ++ch) {
      const int buf = ch & 1;
      const bool hv = ch < 8;
      short8 bA[2], bB[2];
      short8 q0[2], q1[2], q2[2], q3[2];
      f32x4 Pe0{0,0,0,0}, Po0{0,0,0,0}, Pe1{0,0,0,0}, Po1{0,0,0,0};
      if (hv) calcW(ch + 1, (ch + 1) & 1);
      ldB(ch, 0, bA);
      if (hv) { ldQ(0, q0); ldQ(1, q1); }    // issue corners 0,1
      ldB(ch, 1, bB);
      mmah(buf, 0, bA);
      if (hv) {
        ldQ(2, q2); ldQ(3, q3);              // issue corners 2,3
        accQ(q0[0], wg[0], Pe0, Po0); accQ(q0[1], wg[0], Pe1, Po1);
      }
      ldB(ch, 2, bA);
      mmah(buf, 1, bB);
      if (hv) { accQ(q1[0], wg[1], Pe0, Po0); accQ(q1[1], wg[1], Pe1, Po1); }
      ldB(ch, 3, bB);
      if (ch < 7) loadOff(ch + 2, ch & 1);
      mmah(buf, 2, bA);
      if (hv) {
        accQ(q2[0], wg[2], Pe0, Po0); accQ(q2[1], wg[2], Pe1, Po1);
        accQ(q3[0], wg[3], Pe0, Po0); accQ(q3[1], wg[3], Pe1, Po1);
        short8 s0, s1;
        s0[0]=f2bf(Pe0.x); s0[1]=f2bf(Po0.x); s0[2]=f2bf(Pe0.y); s0[3]=f2bf(Po0.y);
        s0[4]=f2bf(Pe0.z); s0[5]=f2bf(Po0.z); s0[6]=f2bf(Pe0.w); s0[7]=f2bf(Po0.w);
        s1[0]=f2bf(Pe1.x); s1[1]=f2bf(Po1.x); s1[2]=f2bf(Pe1.y); s1[3]=f2bf(Po1.y);
        s1[4]=f2bf(Pe1.z); s1[5]=f2bf(Po1.z); s1[6]=f2bf(Pe1.w); s1[7]=f2bf(Po1.w);
        *(short8*)(At[buf ^ 1] + wb)      = s0;
        *(short8*)(At[buf ^ 1] + wb + 16) = s1;
      }
      mmah(buf, 3, bB);
      __syncthreads();
    }
  } else {
    const float* x = (const float*)xsrc;
    auto ldC = [&](int c, f32x4* G) {
      const f32x4* p = (const f32x4*)(x + og[c]);
      G[0] = p[0]; G[1] = p[1]; G[2] = p[2]; G[3] = p[3];
    };
    loadOff(0, 0); loadOff(1, 1);
    calcW(0, 0);
    {
      f32x4 G0[4], G1[4];
      ldC(0, G0); ldC(1, G1);
      f32x4 P0 = wg[0]*G0[0] + wg[1]*G1[0], P1 = wg[0]*G0[1] + wg[1]*G1[1];
      f32x4 P2 = wg[0]*G0[2] + wg[1]*G1[2], P3 = wg[0]*G0[3] + wg[1]*G1[3];
      ldC(2, G0); ldC(3, G1);
      P0 += wg[2]*G0[0] + wg[3]*G1[0]; P1 += wg[2]*G0[1] + wg[3]*G1[1];
      P2 += wg[2]*G0[2] + wg[3]*G1[2]; P3 += wg[2]*G0[3] + wg[3]*G1[3];
      *(short8*)(At[0] + wb)      = pack8(P0, P1);
      *(short8*)(At[0] + wb + 16) = pack8(P2, P3);
    }
    __syncthreads();
#pragma unroll
    for (int ch = 0; ch < 9; ++ch) {
      const int buf = ch & 1;
      const bool hv = ch < 8;
      if (hv) calcW(ch + 1, (ch + 1) & 1);
      short8 bA[2], bB[2];
      f32x4 G0[4], G1[4], P0, P1, P2, P3;
      ldB(ch, 0, bA);
      if (hv) ldC(0, G0);
      ldB(ch, 1, bB);
      mmah(buf, 0, bA);
      if (hv) { P0 = wg[0]*G0[0]; P1 = wg[0]*G0[1]; P2 = wg[0]*G0[2]; P3 = wg[0]*G0[3]; }
      if (hv) ldC(1, G1);
      ldB(ch, 2, bA);
      mmah(buf, 1, bB);
      if (hv) { P0 += wg[1]*G1[0]; P1 += wg[1]*G1[1]; P2 += wg[1]*G1[2]; P3 += wg[1]*G1[3]; }
      if (hv) ldC(2, G0);
      ldB(ch, 3, bB);
      if (ch < 7) loadOff(ch + 2, ch & 1);
      mmah(buf, 2, bA);
      if (hv) { P0 += wg[2]*G0[0]; P1 += wg[2]*G0[1]; P2 += wg[2]*G0[2]; P3 += wg[2]*G0[3]; }
      if (hv) ldC(3, G1);
      mmah(buf, 3, bB);
      if (hv) {
        P0 += wg[3]*G1[0]; P1 += wg[3]*G1[1]; P2 += wg[3]*G1[2]; P3 += wg[3]*G1[3];
        *(short8*)(At[buf ^ 1] + wb)      = pack8(P0, P1);
        *(short8*)(At[buf ^ 1] + wb + 16) = pack8(P2, P3);
      }
      __syncthreads();
    }
  }

  // ---- epilogue: D layout col(F)=lane&15, row(M)=(lane>>4)*4+reg ----
  float bs[2];
#pragma unroll
  for (int nb = 0; nb < 2; ++nb) bs[nb] = bias[wv * 32 + nb * 16 + fr];
  float* orow = out + (long)(b * 64 + oh) * 64 * 256;
#pragma unroll
  for (int m2 = 0; m2 < 4; ++m2) {
#pragma unroll
    for (int j = 0; j < 4; ++j) {
      const int ow = m2 * 16 + kg * 4 + j;
#pragma unroll
      for (int nb = 0; nb < 2; ++nb)
        orow[ow * 256 + wv * 32 + nb * 16 + fr] = acc[m2][nb][j] + bs[nb];
    }
  }
}

extern "C" void kernel_launch(void* const* d_in, const int* in_sizes, int n_in,
                              void* d_out, int out_size, void* d_ws, size_t ws_size,
                              hipStream_t stream) {
  const float* x    = (const float*)d_in[0];
  const float* off  = (const float*)d_in[1];
  const float* mo   = (const float*)d_in[2];
  const float* kf   = (const float*)d_in[3];
  const float* bias = (const float*)d_in[4];
  float* outp = (float*)d_out;
  unsigned short* wtB = (unsigned short*)d_ws;

  wt_prep<<<1152, 256, 0, stream>>>(kf, wtB);
  if (ws_size >= WT_BYTES + XB_BYTES) {
    unsigned short* xb = (unsigned short*)((char*)d_ws + WT_BYTES);
    x_prep<<<1024, 512, 0, stream>>>(x, xb);
    dcn_main<true><<<512, 512, 0, stream>>>(xb, off, mo, wtB, bias, outp);
  } else {
    dcn_main<false><<<512, 512, 0, stream>>>(x, off, mo, wtB, bias, outp);
  }
}